// Round 2
// baseline (435.196 us; speedup 1.0000x reference)
//
#include <hip/hip_runtime.h>
#include <hip/hip_bf16.h>
#include <stdint.h>

#define NB 2
#define NH 16
#define LT 2048
#define LS 2048
#define DIM 1024
#define HD 64

typedef __attribute__((ext_vector_type(4))) float f32x4;
typedef __attribute__((ext_vector_type(8))) short short8;

__device__ __forceinline__ short f2bf(float f) {
  __hip_bfloat16 h = __float2bfloat16(f);
  return *reinterpret_cast<short*>(&h);
}

// ---- weight transpose+cast: W[K][N] fp32 -> Wt[N][K] bf16 (4 weights) ----
__global__ __launch_bounds__(256) void wt_kernel(const float* __restrict__ Wq, const float* __restrict__ Wk,
                                                 const float* __restrict__ Wv, const float* __restrict__ Wo,
                                                 short* __restrict__ wt) {
  __shared__ float tile[64][68];
  const int bid = blockIdx.x;
  const int widx = bid >> 8;
  const int rem = bid & 255;
  const int kt = rem >> 4, nt = rem & 15;
  const float* W = (widx == 0) ? Wq : (widx == 1) ? Wk : (widx == 2) ? Wv : Wo;
  const int tid = threadIdx.x;
  {
    const int r = tid >> 2, c0 = (tid & 3) << 4;
    const float* src = W + (size_t)(kt * 64 + r) * DIM + nt * 64 + c0;
#pragma unroll
    for (int j = 0; j < 4; ++j)
      *reinterpret_cast<f32x4*>(&tile[r][c0 + 4 * j]) = *reinterpret_cast<const f32x4*>(src + 4 * j);
  }
  __syncthreads();
  {
    const int n = tid >> 2, k0 = (tid & 3) << 4;
    short outv[16];
#pragma unroll
    for (int j = 0; j < 16; ++j) outv[j] = f2bf(tile[k0 + j][n]);
    short* dst = wt + (size_t)widx * DIM * DIM + (size_t)(nt * 64 + n) * DIM + kt * 64 + k0;
    *reinterpret_cast<short8*>(dst) = *reinterpret_cast<short8*>(&outv[0]);
    *reinterpret_cast<short8*>(dst + 8) = *reinterpret_cast<short8*>(&outv[8]);
  }
}

// ---- GEMM: C = A[4096][1024] * Bt[N=1024][K=1024]^T (Bt bf16, pre-transposed)
// MODE 0: A fp32, out = bf16 head-split [B,H,L,HD] (Q)
// MODE 1: A fp32, out = fp32 head-split (K/V to d_out) + bf16 copy to ws
// MODE 2: A bf16, out = fp32 row-major [4096][1024] (final proj)
template <int MODE>
__global__ __launch_bounds__(256) void gemm_kernel(const void* __restrict__ Aptr, const short* __restrict__ Bt,
                                                   void* __restrict__ outp, short* __restrict__ out_bf) {
  __shared__ short a_lds[128][40];
  __shared__ short b_lds[128][40];
  const int bm = blockIdx.x & 31, bn = blockIdx.x >> 5;
  const int tid = threadIdx.x;
  const int lane = tid & 63, w = tid >> 6;
  const int wr = w >> 1, wc = w & 1;
  const int lm = lane & 15, g8 = (lane >> 4) << 3;
  f32x4 acc[4][4];
#pragma unroll
  for (int i = 0; i < 4; ++i)
#pragma unroll
    for (int j = 0; j < 4; ++j) acc[i][j] = (f32x4){0.f, 0.f, 0.f, 0.f};

  const int sr = tid >> 1, sc0 = (tid & 1) << 4;
  for (int k0 = 0; k0 < 1024; k0 += 32) {
    __syncthreads();
    short abuf[16];
    if (MODE == 2) {
      const short* src = (const short*)Aptr + (size_t)(bm * 128 + sr) * 1024 + k0 + sc0;
      *reinterpret_cast<short8*>(&abuf[0]) = *reinterpret_cast<const short8*>(src);
      *reinterpret_cast<short8*>(&abuf[8]) = *reinterpret_cast<const short8*>(src + 8);
    } else {
      const float* src = (const float*)Aptr + (size_t)(bm * 128 + sr) * 1024 + k0 + sc0;
#pragma unroll
      for (int j = 0; j < 16; ++j) abuf[j] = f2bf(src[j]);
    }
    *reinterpret_cast<short8*>(&a_lds[sr][sc0]) = *reinterpret_cast<short8*>(&abuf[0]);
    *reinterpret_cast<short8*>(&a_lds[sr][sc0 + 8]) = *reinterpret_cast<short8*>(&abuf[8]);
    const short* bsrc = Bt + (size_t)(bn * 128 + sr) * 1024 + k0 + sc0;
    *reinterpret_cast<short8*>(&b_lds[sr][sc0]) = *reinterpret_cast<const short8*>(bsrc);
    *reinterpret_cast<short8*>(&b_lds[sr][sc0 + 8]) = *reinterpret_cast<const short8*>(bsrc + 8);
    __syncthreads();
    short8 afr[4], bfr[4];
#pragma unroll
    for (int mi = 0; mi < 4; ++mi) afr[mi] = *reinterpret_cast<const short8*>(&a_lds[wr * 64 + mi * 16 + lm][g8]);
#pragma unroll
    for (int nj = 0; nj < 4; ++nj) bfr[nj] = *reinterpret_cast<const short8*>(&b_lds[wc * 64 + nj * 16 + lm][g8]);
#pragma unroll
    for (int mi = 0; mi < 4; ++mi)
#pragma unroll
      for (int nj = 0; nj < 4; ++nj)
        acc[mi][nj] = __builtin_amdgcn_mfma_f32_16x16x32_bf16(afr[mi], bfr[nj], acc[mi][nj], 0, 0, 0);
  }
  const int g4 = (lane >> 4) << 2;
#pragma unroll
  for (int mi = 0; mi < 4; ++mi)
#pragma unroll
    for (int nj = 0; nj < 4; ++nj)
#pragma unroll
      for (int r = 0; r < 4; ++r) {
        const int row = bm * 128 + wr * 64 + mi * 16 + g4 + r;
        const int col = bn * 128 + wc * 64 + nj * 16 + lm;
        const float v = acc[mi][nj][r];
        if (MODE == 2) {
          ((float*)outp)[(size_t)row * DIM + col] = v;
        } else {
          const int b = row >> 11, t = row & 2047, hh = col >> 6, hd = col & 63;
          const size_t idx = (((size_t)b * NH + hh) * LS + t) * HD + hd;
          if (MODE == 0) {
            ((short*)outp)[idx] = f2bf(v);
          } else {
            ((float*)outp)[idx] = v;
            out_bf[idx] = f2bf(v);
          }
        }
      }
}

// ---- fused flash attention v2: softmax(Q K^T / 8 + pe + mask) V ----
// 1 block = 64 q-rows of one (b,h); 4 waves, 16 q-rows each. grid = 32*16*2 = 1024.
__global__ __launch_bounds__(256, 4) void attn_kernel(const short* __restrict__ qw, const short* __restrict__ kbf,
                                                      const short* __restrict__ vbf, const float* __restrict__ pe,
                                                      const float* __restrict__ mask, short* __restrict__ aout) {
  __shared__ short k_lds[64][72];
  __shared__ short vt_lds[64][72];
  __shared__ short p_lds[4][16][72];
  const int bid = blockIdx.x;
  const int qt = bid & 31;
  const int h = (bid >> 5) & 15;
  const int b = bid >> 9;
  const int bh = b * NH + h;
  const int tid = threadIdx.x, lane = tid & 63, w = tid >> 6;
  const int qbase = qt * 64 + w * 16;
  const int lm = lane & 15, g = lane >> 4, g8 = g << 3, g4 = g << 2;

  // Q fragment: 16 q-rows x 64 d, held in regs for the whole kernel
  short8 qfr[2];
#pragma unroll
  for (int kk = 0; kk < 2; ++kk)
    qfr[kk] = *reinterpret_cast<const short8*>(qw + ((size_t)bh * LT + qbase + lm) * HD + kk * 32 + g8);

  f32x4 acc_o[4];
  float m_run[4], l_run[4];
#pragma unroll
  for (int dj = 0; dj < 4; ++dj) acc_o[dj] = (f32x4){0.f, 0.f, 0.f, 0.f};
#pragma unroll
  for (int r = 0; r < 4; ++r) {
    m_run[r] = -1e30f;
    l_run[r] = 0.f;
  }

  const float* peh = pe + (size_t)h * LT * LS;
  const int srow = tid >> 2, scol0 = (tid & 3) << 4;  // K staging: 4 lanes per row (coalesced)
  const int vc0 = w << 4;                             // V staging: lane = s-row, wave = 16-d slab

  for (int s0 = 0; s0 < LS; s0 += 64) {
    // stage K tile [64 s][64 d]
    {
      const short* ksrc = kbf + ((size_t)bh * LS + s0 + srow) * HD + scol0;
      *reinterpret_cast<short8*>(&k_lds[srow][scol0]) = *reinterpret_cast<const short8*>(ksrc);
      *reinterpret_cast<short8*>(&k_lds[srow][scol0 + 8]) = *reinterpret_cast<const short8*>(ksrc + 8);
    }
    // stage V^T tile [64 d][64 s]: lane loads V[s0+lane][vc0..vc0+15], writes columns
    {
      const short* vsrc = vbf + ((size_t)bh * LS + s0 + lane) * HD + vc0;
      short vv[16];
      *reinterpret_cast<short8*>(&vv[0]) = *reinterpret_cast<const short8*>(vsrc);
      *reinterpret_cast<short8*>(&vv[8]) = *reinterpret_cast<const short8*>(vsrc + 8);
#pragma unroll
      for (int j = 0; j < 16; ++j) vt_lds[vc0 + j][lane] = vv[j];  // full row per j: conflict-free
    }
    __syncthreads();

    // S = Q K^T (16 q-rows x 64 s-cols per wave)
    f32x4 accs[4];
#pragma unroll
    for (int nj = 0; nj < 4; ++nj) {
      accs[nj] = (f32x4){0.f, 0.f, 0.f, 0.f};
#pragma unroll
      for (int kk = 0; kk < 2; ++kk) {
        const short8 kfr = *reinterpret_cast<const short8*>(&k_lds[nj * 16 + lm][kk * 32 + g8]);
        accs[nj] = __builtin_amdgcn_mfma_f32_16x16x32_bf16(qfr[kk], kfr, accs[nj], 0, 0, 0);
      }
    }

    // scale + pe + mask, online softmax (row t spans 16 lanes x 4 nj)
#pragma unroll
    for (int r = 0; r < 4; ++r) {
      const int t = qbase + g4 + r;
      float sv[4];
#pragma unroll
      for (int nj = 0; nj < 4; ++nj) {
        const int s = s0 + nj * 16 + lm;
        sv[nj] = fmaf(accs[nj][r], 0.125f, peh[(size_t)t * LS + s] + mask[(size_t)t * LS + s]);
      }
      float mx = fmaxf(fmaxf(sv[0], sv[1]), fmaxf(sv[2], sv[3]));
      mx = fmaxf(mx, __shfl_xor(mx, 1));
      mx = fmaxf(mx, __shfl_xor(mx, 2));
      mx = fmaxf(mx, __shfl_xor(mx, 4));
      mx = fmaxf(mx, __shfl_xor(mx, 8));
      const float mnew = fmaxf(m_run[r], mx);
      const float sc = __expf(m_run[r] - mnew);
      m_run[r] = mnew;
      float rs = 0.f;
#pragma unroll
      for (int nj = 0; nj < 4; ++nj) {
        sv[nj] = __expf(sv[nj] - mnew);
        rs += sv[nj];
      }
      rs += __shfl_xor(rs, 1);
      rs += __shfl_xor(rs, 2);
      rs += __shfl_xor(rs, 4);
      rs += __shfl_xor(rs, 8);
      l_run[r] = l_run[r] * sc + rs;
#pragma unroll
      for (int dj = 0; dj < 4; ++dj) acc_o[dj][r] *= sc;
#pragma unroll
      for (int nj = 0; nj < 4; ++nj) p_lds[w][g4 + r][nj * 16 + lm] = f2bf(sv[nj]);
    }
    // NO barrier: p_lds is wave-private (lgkmcnt ordering suffices); vt_lds synced above.

    // O += P V
#pragma unroll
    for (int kk = 0; kk < 2; ++kk) {
      const short8 pfr = *reinterpret_cast<const short8*>(&p_lds[w][lm][kk * 32 + g8]);
#pragma unroll
      for (int dj = 0; dj < 4; ++dj) {
        const short8 vfr = *reinterpret_cast<const short8*>(&vt_lds[dj * 16 + lm][kk * 32 + g8]);
        acc_o[dj] = __builtin_amdgcn_mfma_f32_16x16x32_bf16(pfr, vfr, acc_o[dj], 0, 0, 0);
      }
    }
    __syncthreads();  // protect k_lds/vt_lds before next stage
  }

  // epilogue: normalize, write bf16 score_cat layout [B, LT, H*HD]
#pragma unroll
  for (int r = 0; r < 4; ++r) {
    const float inv = 1.f / l_run[r];
    const int t = qbase + g4 + r;
#pragma unroll
    for (int dj = 0; dj < 4; ++dj) {
      const int d = dj * 16 + lm;
      aout[((size_t)b * LT + t) * DIM + h * HD + d] = f2bf(acc_o[dj][r] * inv);
    }
  }
}

extern "C" void kernel_launch(void* const* d_in, const int* in_sizes, int n_in, void* d_out, int out_size,
                              void* d_ws, size_t ws_size, hipStream_t stream) {
  (void)in_sizes;
  (void)n_in;
  (void)out_size;
  (void)ws_size;
  const float* x = (const float*)d_in[0];
  const float* memory = (const float*)d_in[1];
  const float* pe = (const float*)d_in[2];
  const float* mask = (const float*)d_in[3];
  const float* Wq = (const float*)d_in[4];
  const float* Wk = (const float*)d_in[5];
  const float* Wv = (const float*)d_in[6];
  const float* Wo = (const float*)d_in[7];
  float* outp = (float*)d_out;
  float* k_out = outp + (size_t)NB * NH * LS * HD;
  float* v_out = k_out + (size_t)NB * NH * LS * HD;
  char* ws = (char*)d_ws;
  short* q_ws = (short*)ws;                      //  8 MiB: Q bf16 [B,H,LT,HD]
  short* attn_ws = (short*)(ws + (8u << 20));    //  8 MiB: attn out bf16 [B,LT,D]
  short* wt = (short*)(ws + (16u << 20));        //  8 MiB: 4x Wt bf16 [N][K]
  short* k_bf = (short*)(ws + (24u << 20));      //  8 MiB: K bf16 [B,H,LS,HD]
  short* v_bf = (short*)(ws + (32u << 20));      //  8 MiB: V bf16 [B,H,LS,HD]

  wt_kernel<<<dim3(1024), dim3(256), 0, stream>>>(Wq, Wk, Wv, Wo, wt);
  gemm_kernel<0><<<dim3(256), dim3(256), 0, stream>>>(x, wt, (void*)q_ws, nullptr);
  gemm_kernel<1><<<dim3(256), dim3(256), 0, stream>>>(memory, wt + (1u << 20), (void*)k_out, k_bf);
  gemm_kernel<1><<<dim3(256), dim3(256), 0, stream>>>(memory, wt + (2u << 20), (void*)v_out, v_bf);
  attn_kernel<<<dim3(1024), dim3(256), 0, stream>>>(q_ws, k_bf, v_bf, pe, mask, attn_ws);
  gemm_kernel<2><<<dim3(256), dim3(256), 0, stream>>>(attn_ws, wt + (3u << 20), (void*)outp, nullptr);
}

// Round 3
// 342.070 us; speedup vs baseline: 1.2722x; 1.2722x over previous
//
#include <hip/hip_runtime.h>
#include <hip/hip_bf16.h>
#include <stdint.h>

#define NB 2
#define NH 16
#define LT 2048
#define LS 2048
#define DIM 1024
#define HD 64

typedef __attribute__((ext_vector_type(4))) float f32x4;
typedef __attribute__((ext_vector_type(8))) short short8;
typedef __attribute__((ext_vector_type(4))) short short4v;
typedef __attribute__((ext_vector_type(2))) short short2v;

__device__ __forceinline__ short f2bf(float f) {
  __hip_bfloat16 h = __float2bfloat16(f);
  return *reinterpret_cast<short*>(&h);
}

// ---- weight transpose+cast: W[K][N] fp32 -> Wt[N][K] bf16 (4 weights) ----
__global__ __launch_bounds__(256) void wt_kernel(const float* __restrict__ Wq, const float* __restrict__ Wk,
                                                 const float* __restrict__ Wv, const float* __restrict__ Wo,
                                                 short* __restrict__ wt) {
  __shared__ float tile[64][68];
  const int bid = blockIdx.x;
  const int widx = bid >> 8;
  const int rem = bid & 255;
  const int kt = rem >> 4, nt = rem & 15;
  const float* W = (widx == 0) ? Wq : (widx == 1) ? Wk : (widx == 2) ? Wv : Wo;
  const int tid = threadIdx.x;
  {
    const int r = tid >> 2, c0 = (tid & 3) << 4;
    const float* src = W + (size_t)(kt * 64 + r) * DIM + nt * 64 + c0;
#pragma unroll
    for (int j = 0; j < 4; ++j)
      *reinterpret_cast<f32x4*>(&tile[r][c0 + 4 * j]) = *reinterpret_cast<const f32x4*>(src + 4 * j);
  }
  __syncthreads();
  {
    const int n = tid >> 2, k0 = (tid & 3) << 4;
    short outv[16];
#pragma unroll
    for (int j = 0; j < 16; ++j) outv[j] = f2bf(tile[k0 + j][n]);
    short* dst = wt + (size_t)widx * DIM * DIM + (size_t)(nt * 64 + n) * DIM + kt * 64 + k0;
    *reinterpret_cast<short8*>(dst) = *reinterpret_cast<short8*>(&outv[0]);
    *reinterpret_cast<short8*>(dst + 8) = *reinterpret_cast<short8*>(&outv[8]);
  }
}

// ---- GEMM: C = A[4096][1024] * Bt[N=1024][K=1024]^T (Bt bf16, pre-transposed)
template <int MODE>
__global__ __launch_bounds__(256) void gemm_kernel(const void* __restrict__ Aptr, const short* __restrict__ Bt,
                                                   void* __restrict__ outp, short* __restrict__ out_bf) {
  __shared__ short a_lds[128][40];
  __shared__ short b_lds[128][40];
  const int bm = blockIdx.x & 31, bn = blockIdx.x >> 5;
  const int tid = threadIdx.x;
  const int lane = tid & 63, w = tid >> 6;
  const int wr = w >> 1, wc = w & 1;
  const int lm = lane & 15, g8 = (lane >> 4) << 3;
  f32x4 acc[4][4];
#pragma unroll
  for (int i = 0; i < 4; ++i)
#pragma unroll
    for (int j = 0; j < 4; ++j) acc[i][j] = (f32x4){0.f, 0.f, 0.f, 0.f};

  const int sr = tid >> 1, sc0 = (tid & 1) << 4;
  for (int k0 = 0; k0 < 1024; k0 += 32) {
    __syncthreads();
    short abuf[16];
    if (MODE == 2) {
      const short* src = (const short*)Aptr + (size_t)(bm * 128 + sr) * 1024 + k0 + sc0;
      *reinterpret_cast<short8*>(&abuf[0]) = *reinterpret_cast<const short8*>(src);
      *reinterpret_cast<short8*>(&abuf[8]) = *reinterpret_cast<const short8*>(src + 8);
    } else {
      const float* src = (const float*)Aptr + (size_t)(bm * 128 + sr) * 1024 + k0 + sc0;
#pragma unroll
      for (int j = 0; j < 16; ++j) abuf[j] = f2bf(src[j]);
    }
    *reinterpret_cast<short8*>(&a_lds[sr][sc0]) = *reinterpret_cast<short8*>(&abuf[0]);
    *reinterpret_cast<short8*>(&a_lds[sr][sc0 + 8]) = *reinterpret_cast<short8*>(&abuf[8]);
    const short* bsrc = Bt + (size_t)(bn * 128 + sr) * 1024 + k0 + sc0;
    *reinterpret_cast<short8*>(&b_lds[sr][sc0]) = *reinterpret_cast<const short8*>(bsrc);
    *reinterpret_cast<short8*>(&b_lds[sr][sc0 + 8]) = *reinterpret_cast<const short8*>(bsrc + 8);
    __syncthreads();
    short8 afr[4], bfr[4];
#pragma unroll
    for (int mi = 0; mi < 4; ++mi) afr[mi] = *reinterpret_cast<const short8*>(&a_lds[wr * 64 + mi * 16 + lm][g8]);
#pragma unroll
    for (int nj = 0; nj < 4; ++nj) bfr[nj] = *reinterpret_cast<const short8*>(&b_lds[wc * 64 + nj * 16 + lm][g8]);
#pragma unroll
    for (int mi = 0; mi < 4; ++mi)
#pragma unroll
      for (int nj = 0; nj < 4; ++nj)
        acc[mi][nj] = __builtin_amdgcn_mfma_f32_16x16x32_bf16(afr[mi], bfr[nj], acc[mi][nj], 0, 0, 0);
  }
  const int g4 = (lane >> 4) << 2;
#pragma unroll
  for (int mi = 0; mi < 4; ++mi)
#pragma unroll
    for (int nj = 0; nj < 4; ++nj)
#pragma unroll
      for (int r = 0; r < 4; ++r) {
        const int row = bm * 128 + wr * 64 + mi * 16 + g4 + r;
        const int col = bn * 128 + wc * 64 + nj * 16 + lm;
        const float v = acc[mi][nj][r];
        if (MODE == 2) {
          ((float*)outp)[(size_t)row * DIM + col] = v;
        } else {
          const int b = row >> 11, t = row & 2047, hh = col >> 6, hd = col & 63;
          const size_t idx = (((size_t)b * NH + hh) * LS + t) * HD + hd;
          if (MODE == 0) {
            ((short*)outp)[idx] = f2bf(v);
          } else {
            ((float*)outp)[idx] = v;
            out_bf[idx] = f2bf(v);
          }
        }
      }
}

// ---- fused flash attention v3: swapped-QK layout, vectorized pe/mask loads ----
// 1 block = 64 q-rows of one (b,h); 4 waves, 16 q-rows each. grid = 1024.
// bid mapping pairs b=0/b=1 for the same (h,qt) so pe rows are L2/L3-hot.
__global__ __launch_bounds__(256, 4) void attn_kernel(const short* __restrict__ qw, const short* __restrict__ kbf,
                                                      const short* __restrict__ vbf, const float* __restrict__ pe,
                                                      const float* __restrict__ mask, short* __restrict__ aout) {
  __shared__ short k_lds[64][72];
  __shared__ short vt_lds[64][72];
  __shared__ short p_lds[4][16][72];
  __shared__ float sc_lds[4][16];
  __shared__ float l_lds[4][16];
  const int bid = blockIdx.x;
  const int b = bid & 1;
  const int qt = (bid >> 1) & 31;
  const int h = (bid >> 6) & 15;
  const int bh = b * NH + h;
  const int tid = threadIdx.x, lane = tid & 63, w = tid >> 6;
  const int qbase = qt * 64 + w * 16;
  const int lm = lane & 15, g = lane >> 4, g8 = g << 3, g4 = g << 2;
  constexpr float L2E = 1.4426950408889634f;

  // Q fragment (B-operand of swapped QK): lane lm <-> q-row qbase+lm
  short8 qfr[2];
#pragma unroll
  for (int kk = 0; kk < 2; ++kk)
    qfr[kk] = *reinterpret_cast<const short8*>(qw + ((size_t)bh * LT + qbase + lm) * HD + kk * 32 + g8);

  // per-lane softmax state for t = qbase+lm (replicated across the 4 lane groups)
  float m_run = -1e30f, l_run = 0.f;
  f32x4 acc_o[4];  // O[t=qbase+g4+r][d=dj*16+lm]
#pragma unroll
  for (int dj = 0; dj < 4; ++dj) acc_o[dj] = (f32x4){0.f, 0.f, 0.f, 0.f};

  const int t_lane = qbase + lm;
  const float* pe_row = pe + (size_t)h * LT * LS + (size_t)t_lane * LS;
  const float* mask_row = mask + (size_t)t_lane * LS;

  // staging assignments
  const int srow = tid >> 2, scol0 = (tid & 3) << 4;           // K: 4 lanes per row
  const int vs2 = (lane & 31) << 1;                            // V: rows vs2, vs2+1
  const int vd0 = (w << 4) + ((lane >> 5) << 3);               // V: 8-d slab

  for (int s0 = 0; s0 < LS; s0 += 64) {
    // stage K tile [64 s][64 d] (2x b128 writes)
    {
      const short* ksrc = kbf + ((size_t)bh * LS + s0 + srow) * HD + scol0;
      *reinterpret_cast<short8*>(&k_lds[srow][scol0]) = *reinterpret_cast<const short8*>(ksrc);
      *reinterpret_cast<short8*>(&k_lds[srow][scol0 + 8]) = *reinterpret_cast<const short8*>(ksrc + 8);
    }
    // stage V^T tile [64 d][64 s]: paired rows -> 8x b32 writes, conflict-free
    {
      const short* vsrc = vbf + ((size_t)bh * LS + s0 + vs2) * HD + vd0;
      const short8 va = *reinterpret_cast<const short8*>(vsrc);
      const short8 vb = *reinterpret_cast<const short8*>(vsrc + HD);
#pragma unroll
      for (int j = 0; j < 8; ++j) {
        short2v pr = {va[j], vb[j]};
        *reinterpret_cast<short2v*>(&vt_lds[vd0 + j][vs2]) = pr;
      }
    }
    __syncthreads();

    // issue pe/mask vector loads early (independent of MFMA)
    f32x4 pv4[4], mv4[4];
#pragma unroll
    for (int nj = 0; nj < 4; ++nj) {
      const int sbase = s0 + nj * 16 + g4;
      pv4[nj] = *reinterpret_cast<const f32x4*>(pe_row + sbase);
      mv4[nj] = *reinterpret_cast<const f32x4*>(mask_row + sbase);
    }

    // S^T = K Q^T : accs[nj][r] = S[s = s0+nj*16+g4+r][t = qbase+lm]
    f32x4 accs[4];
#pragma unroll
    for (int nj = 0; nj < 4; ++nj) {
      accs[nj] = (f32x4){0.f, 0.f, 0.f, 0.f};
#pragma unroll
      for (int kk = 0; kk < 2; ++kk) {
        const short8 kfr = *reinterpret_cast<const short8*>(&k_lds[nj * 16 + lm][kk * 32 + g8]);
        accs[nj] = __builtin_amdgcn_mfma_f32_16x16x32_bf16(kfr, qfr[kk], accs[nj], 0, 0, 0);
      }
    }

    // softmax over s for this lane's row t (16 local values + 2 shuffles)
#pragma unroll
    for (int nj = 0; nj < 4; ++nj)
#pragma unroll
      for (int r = 0; r < 4; ++r) accs[nj][r] = fmaf(accs[nj][r], 0.125f, pv4[nj][r] + mv4[nj][r]);

    float mx = accs[0][0];
#pragma unroll
    for (int nj = 0; nj < 4; ++nj)
#pragma unroll
      for (int r = 0; r < 4; ++r) mx = fmaxf(mx, accs[nj][r]);
    mx = fmaxf(mx, __shfl_xor(mx, 16));
    mx = fmaxf(mx, __shfl_xor(mx, 32));
    const float mnew = fmaxf(m_run, mx);
    const float nm = mnew * L2E;
    float rs = 0.f;
#pragma unroll
    for (int nj = 0; nj < 4; ++nj)
#pragma unroll
      for (int r = 0; r < 4; ++r) {
        const float p = exp2f(fmaf(accs[nj][r], L2E, -nm));
        accs[nj][r] = p;
        rs += p;
      }
    rs += __shfl_xor(rs, 16);
    rs += __shfl_xor(rs, 32);
    const float sc = exp2f(fmaf(m_run, L2E, -nm));  // exp(m_run - mnew)
    l_run = l_run * sc + rs;
    m_run = mnew;

    // write P[t][s] (4x b64 writes per lane)
#pragma unroll
    for (int nj = 0; nj < 4; ++nj) {
      short4v pk = {f2bf(accs[nj][0]), f2bf(accs[nj][1]), f2bf(accs[nj][2]), f2bf(accs[nj][3])};
      *reinterpret_cast<short4v*>(&p_lds[w][lm][nj * 16 + g4]) = pk;
    }
    // redistribute per-t rescale factor (t=lm layout -> t=g4+r layout), wave-private
    if (g == 0) sc_lds[w][lm] = sc;
    const f32x4 sc4 = *reinterpret_cast<const f32x4*>(&sc_lds[w][g4]);
#pragma unroll
    for (int dj = 0; dj < 4; ++dj)
#pragma unroll
      for (int r = 0; r < 4; ++r) acc_o[dj][r] *= sc4[r];

    // O += P V
#pragma unroll
    for (int kk = 0; kk < 2; ++kk) {
      const short8 pfr = *reinterpret_cast<const short8*>(&p_lds[w][lm][kk * 32 + g8]);
#pragma unroll
      for (int dj = 0; dj < 4; ++dj) {
        const short8 vfr = *reinterpret_cast<const short8*>(&vt_lds[dj * 16 + lm][kk * 32 + g8]);
        acc_o[dj] = __builtin_amdgcn_mfma_f32_16x16x32_bf16(pfr, vfr, acc_o[dj], 0, 0, 0);
      }
    }
    __syncthreads();  // protect k_lds/vt_lds before next stage
  }

  // epilogue: redistribute 1/l, write bf16 score_cat layout [B, LT, H*HD]
  if (g == 0) l_lds[w][lm] = l_run;
  const f32x4 l4 = *reinterpret_cast<const f32x4*>(&l_lds[w][g4]);
#pragma unroll
  for (int r = 0; r < 4; ++r) {
    const float inv = 1.f / l4[r];
    const int t = qbase + g4 + r;
#pragma unroll
    for (int dj = 0; dj < 4; ++dj) {
      const int d = dj * 16 + lm;
      aout[((size_t)b * LT + t) * DIM + h * HD + d] = f2bf(acc_o[dj][r] * inv);
    }
  }
}

extern "C" void kernel_launch(void* const* d_in, const int* in_sizes, int n_in, void* d_out, int out_size,
                              void* d_ws, size_t ws_size, hipStream_t stream) {
  (void)in_sizes;
  (void)n_in;
  (void)out_size;
  (void)ws_size;
  const float* x = (const float*)d_in[0];
  const float* memory = (const float*)d_in[1];
  const float* pe = (const float*)d_in[2];
  const float* mask = (const float*)d_in[3];
  const float* Wq = (const float*)d_in[4];
  const float* Wk = (const float*)d_in[5];
  const float* Wv = (const float*)d_in[6];
  const float* Wo = (const float*)d_in[7];
  float* outp = (float*)d_out;
  float* k_out = outp + (size_t)NB * NH * LS * HD;
  float* v_out = k_out + (size_t)NB * NH * LS * HD;
  char* ws = (char*)d_ws;
  short* q_ws = (short*)ws;                      //  8 MiB: Q bf16 [B,H,LT,HD]
  short* attn_ws = (short*)(ws + (8u << 20));    //  8 MiB: attn out bf16 [B,LT,D]
  short* wt = (short*)(ws + (16u << 20));        //  8 MiB: 4x Wt bf16 [N][K]
  short* k_bf = (short*)(ws + (24u << 20));      //  8 MiB: K bf16 [B,H,LS,HD]
  short* v_bf = (short*)(ws + (32u << 20));      //  8 MiB: V bf16 [B,H,LS,HD]

  wt_kernel<<<dim3(1024), dim3(256), 0, stream>>>(Wq, Wk, Wv, Wo, wt);
  gemm_kernel<0><<<dim3(256), dim3(256), 0, stream>>>(x, wt, (void*)q_ws, nullptr);
  gemm_kernel<1><<<dim3(256), dim3(256), 0, stream>>>(memory, wt + (1u << 20), (void*)k_out, k_bf);
  gemm_kernel<1><<<dim3(256), dim3(256), 0, stream>>>(memory, wt + (2u << 20), (void*)v_out, v_bf);
  attn_kernel<<<dim3(1024), dim3(256), 0, stream>>>(q_ws, k_bf, v_bf, pe, mask, attn_ws);
  gemm_kernel<2><<<dim3(256), dim3(256), 0, stream>>>(attn_ws, wt + (3u << 20), (void*)outp, nullptr);
}